// Round 15
// baseline (1093.578 us; speedup 1.0000x reference)
//
#include <hip/hip_runtime.h>
#include <math.h>

#define EPS_BN 1e-5f

// Wire formats: float inputs bf16 (runtime-detected), ints int32/int64 (detected), OUTPUT FP32.
// r12: MFMA conv kernels. r13: MFMA lin5. r14: pool re-grid. 
// r15: mbuf ELIMINATED. Key identity: max_e bn(m_e) = bn(max_e m_e) for sc>0,
// = bn(min_e m_e) for sc<0  -> aggregate raw min/max (order-preserving uint atomics,
// edges bucket-ordered), apply BN after pooling. conv1_l2+l3 fused (z1/m2 recomputed);
// aggregation fused into conv tails. 1.2 GB of mbuf round-trip traffic removed.

typedef short short8_t __attribute__((ext_vector_type(8)));
typedef float f32x4_t  __attribute__((ext_vector_type(4)));

// ---------- helpers ----------
static __device__ __forceinline__ float bf2f(unsigned short b){
  return __uint_as_float(((unsigned)b) << 16);
}
static __device__ __forceinline__ unsigned short f2bf(float f){
  unsigned u = __float_as_uint(f);
  u += 0x7fffu + ((u >> 16) & 1u);   // RNE (finite values only)
  return (unsigned short)(u >> 16);
}
static inline int cdiv(int a, int b){ return (a + b - 1) / b; }
static __device__ __forceinline__ int clampi(int v, int lo, int hi){
  return v < lo ? lo : (v > hi ? hi : v);
}
static __device__ __forceinline__ int ld_idx(const void* p, long e, int m64){
  return m64 ? (int)((const long long*)p)[e] : ((const int*)p)[e];
}
// order-preserving float<->uint (uint compare == float compare)
static __device__ __forceinline__ unsigned ordf(float f){
  unsigned b = __float_as_uint(f);
  return (b & 0x80000000u) ? ~b : (b | 0x80000000u);
}
static __device__ __forceinline__ float iordf(unsigned u){
  unsigned b = (u & 0x80000000u) ? (u & 0x7FFFFFFFu) : ~u;
  return __uint_as_float(b);
}

// ---------- sentinel ----------
__global__ void k_sentinel(float* out, int n){
  int i = blockIdx.x*256 + threadIdx.x;
  if (i < n) out[i] = -12288.0f;
}

// ---------- runtime dtype detection ----------
__global__ void k_detect(const void* ei, const void* pos, int* dmode){
  __shared__ int nz, ff;
  if (threadIdx.x == 0){ nz = 0; ff = 0; }
  __syncthreads();
  const int* w32 = (const int*)ei;
  if (w32[1 + 2*threadIdx.x] != 0) nz = 1;
  const unsigned short* ph = (const unsigned short*)pos;
  int bad = 0;
  for (int i = threadIdx.x; i < 8192; i += 256)
    if (((ph[i] >> 7) & 0xFF) == 0xFF) bad = 1;
  if (bad) ff = 1;
  __syncthreads();
  if (threadIdx.x == 0){ dmode[0] = nz ? 0 : 1; dmode[1] = ff; }
}

// ---------- expand float inputs -> fp32 scratch ----------
struct ExpItem { const void* s; float* d; int n; };
struct ExpArgs { ExpItem it[31]; };
__global__ void k_expand(ExpArgs a, int cnt, const int* dmode){
  int i = blockIdx.y;
  if (i >= cnt) return;
  int m32 = dmode[1];
  int t = blockIdx.x*256 + threadIdx.x;
  if (t < a.it[i].n){
    a.it[i].d[t] = m32 ? ((const float*)a.it[i].s)[t]
                       : bf2f(((const unsigned short*)a.it[i].s)[t]);
  }
}

// ---------- Wab prep: [64][128] = [Wa | Wb] ----------
__global__ void k_prepW4(const float* __restrict__ W4, float* __restrict__ Wab){
  int i = blockIdx.x*256 + threadIdx.x;
  if (i < 8192){
    int c = i >> 7, k = i & 127;
    float v;
    if (k < 64) v = W4[c*128 + k] - W4[c*128 + 64 + k];
    else        v = W4[c*128 + k];
    Wab[i] = v;
  }
}

// ---------- CSR build ----------
__global__ void k_hist(const void* __restrict__ ei, int E, int N, const int* dmode, int* __restrict__ deg){
  int m64 = dmode[0];
  int e = blockIdx.x*256 + threadIdx.x;
  if (e < E) atomicAdd(&deg[clampi(ld_idx(ei, (long)E + e, m64), 0, N-1)], 1);
}

__global__ void k_scan1(const int* __restrict__ deg, int N, int* __restrict__ incl, int* __restrict__ part){
  __shared__ int s[1024];
  int i = blockIdx.x*1024 + threadIdx.x;
  s[threadIdx.x] = (i < N) ? deg[i] : 0;
  __syncthreads();
  for (int off = 1; off < 1024; off <<= 1){
    int t = (threadIdx.x >= off) ? s[threadIdx.x - off] : 0;
    __syncthreads();
    s[threadIdx.x] += t;
    __syncthreads();
  }
  if (i < N) incl[i] = s[threadIdx.x];
  if (threadIdx.x == 1023) part[blockIdx.x] = s[1023];
}

__global__ void k_scan2(int* __restrict__ part, int nb){
  __shared__ int s[1024];
  int i = threadIdx.x;
  s[i] = (i < nb) ? part[i] : 0;
  __syncthreads();
  for (int off = 1; off < 1024; off <<= 1){
    int t = (i >= off) ? s[i - off] : 0;
    __syncthreads();
    s[i] += t;
    __syncthreads();
  }
  if (i < nb) part[i] = s[i];
}

__global__ void k_scan3(const int* __restrict__ deg, const int* __restrict__ part, int N, int E,
                        int* __restrict__ offs, int* __restrict__ cursor){
  int i = blockIdx.x*1024 + threadIdx.x;
  if (i < N){
    int prev = (blockIdx.x > 0) ? part[blockIdx.x - 1] : 0;
    int v = prev + offs[i] - deg[i];
    offs[i] = v;
    cursor[i] = v;
  }
  if (blockIdx.x == 0 && threadIdx.x == 0) offs[N] = E;
}

__global__ void k_fill(const void* __restrict__ ei, int E, int N, const int* dmode,
                       int* __restrict__ cursor, int* __restrict__ bucket, int* __restrict__ nodeof){
  int m64 = dmode[0];
  int e = blockIdx.x*256 + threadIdx.x;
  if (e < E){
    int nd = clampi(ld_idx(ei, (long)E + e, m64), 0, N-1);
    int p = atomicAdd(&cursor[nd], 1);
    if (p >= 0 && p < E){ bucket[p] = e; nodeof[p] = nd; }
  }
}

// ---------- conv1 layer1 stats ----------
__global__ void __launch_bounds__(256, 1)
k_m1stats(const float* __restrict__ pos, const void* __restrict__ ei,
          int E, int N, const int* dmode,
          const float* __restrict__ W1, const float* __restrict__ b1,
          float* __restrict__ repl){
  int m64 = dmode[0];
  int lane = threadIdx.x & 63;
  int flatwave = (blockIdx.x*256 + threadIdx.x) >> 6;
  long base = (long)flatwave * 512;
  float as[64], aq[64];
  #pragma unroll
  for (int c = 0; c < 64; c++){ as[c] = 0.f; aq[c] = 0.f; }
  for (int k = 0; k < 8; k++){
    long e = base + (long)k*64 + lane;
    if (e < E){
      int si = clampi(ld_idx(ei, e, m64), 0, N-1);
      int di = clampi(ld_idx(ei, (long)E + e, m64), 0, N-1);
      float x0 = pos[di*3+0], x1 = pos[di*3+1], x2 = pos[di*3+2];
      float j0 = pos[si*3+0]-x0, j1 = pos[si*3+1]-x1, j2 = pos[si*3+2]-x2;
      #pragma unroll
      for (int c = 0; c < 64; c++){
        float m = b1[c];
        m = fmaf(x0, W1[c*6+0], m); m = fmaf(x1, W1[c*6+1], m); m = fmaf(x2, W1[c*6+2], m);
        m = fmaf(j0, W1[c*6+3], m); m = fmaf(j1, W1[c*6+4], m); m = fmaf(j2, W1[c*6+5], m);
        as[c] += m; aq[c] += m*m;
      }
    }
  }
  float outs = 0.f, outq = 0.f;
  #pragma unroll
  for (int c = 0; c < 64; c++){
    float s = as[c], q = aq[c];
    #pragma unroll
    for (int m = 1; m < 64; m <<= 1){ s += __shfl_xor(s, m, 64); q += __shfl_xor(q, m, 64); }
    if (lane == c){ outs = s; outq = q; }
  }
  int r = flatwave & 63;
  atomicAdd(&repl[r*256 + lane], outs);
  atomicAdd(&repl[r*256 + 128 + lane], outq);
}

// ---------- finalize BN ----------
__global__ void k_finalize(float* __restrict__ repl, int C, float count,
                           const float* __restrict__ g, const float* __restrict__ be,
                           float* __restrict__ ss){
  int c = threadIdx.x;
  if (c < C){
    float s = 0.f, q = 0.f;
    for (int r = 0; r < 64; r++){
      s += repl[r*256 + c];       repl[r*256 + c] = 0.f;
      q += repl[r*256 + 128 + c]; repl[r*256 + 128 + c] = 0.f;
    }
    float mean = s / count;
    float var  = fmaxf(q / count - mean*mean, 0.f);
    float inv  = rsqrtf(var + EPS_BN);
    float sc   = g[c] * inv;
    ss[c]     = sc;
    ss[C + c] = be[c] - mean*sc;
  }
}

// ---------- MFMA building blocks ----------
// A layout (m120): lane holds A[m=lane&15][k=(lane>>4)*8+j]
// C/D layout (m89/m91): col=lane&15, row=(lane>>4)*4+reg
template<int KT>
static __device__ __forceinline__ void loadB(const float* __restrict__ Wp, int c15, int q,
                                             short8_t bf[4][KT]){
  #pragma unroll
  for (int nt = 0; nt < 4; nt++){
    int c = nt*16 + c15;
    #pragma unroll
    for (int kt = 0; kt < KT; kt++){
      const float* wr = Wp + (size_t)c*(KT*32) + kt*32 + q*8;
      union { short8_t v; unsigned short u[8]; } pb;
      #pragma unroll
      for (int j = 0; j < 8; j++) pb.u[j] = f2bf(wr[j]);
      bf[nt][kt] = pb.v;
    }
  }
}
template<int KT, int ST>
static __device__ __forceinline__ void do_mfma(const unsigned short* Aw, short8_t bf[4][KT],
                                               const float* __restrict__ bias, int c15, int q,
                                               f32x4_t acc[4][4]){
  #pragma unroll
  for (int mt = 0; mt < 4; mt++)
    #pragma unroll
    for (int nt = 0; nt < 4; nt++){
      float bv = bias[nt*16 + c15];
      acc[mt][nt] = (f32x4_t){bv, bv, bv, bv};
    }
  #pragma unroll
  for (int mt = 0; mt < 4; mt++){
    #pragma unroll
    for (int kt = 0; kt < KT; kt++){
      short8_t af = *(const short8_t*)&Aw[(mt*16 + c15)*ST + kt*32 + q*8];
      #pragma unroll
      for (int nt = 0; nt < 4; nt++)
        acc[mt][nt] = __builtin_amdgcn_mfma_f32_16x16x32_bf16(af, bf[nt][kt], acc[mt][nt], 0, 0, 0);
    }
  }
}
static __device__ __forceinline__ void stats_acc(f32x4_t acc[4][4], long tb, int E,
                                                 int lane, int q, int r_idx,
                                                 float* __restrict__ repl){
  #pragma unroll
  for (int nt = 0; nt < 4; nt++){
    float s = 0.f, qq = 0.f;
    #pragma unroll
    for (int mt = 0; mt < 4; mt++){
      #pragma unroll
      for (int r = 0; r < 4; r++){
        long eidx = tb + mt*16 + q*4 + r;
        float v = (eidx < E) ? acc[mt][nt][r] : 0.f;
        s += v; qq += v*v;
      }
    }
    s += __shfl_xor(s, 16, 64); qq += __shfl_xor(qq, 16, 64);
    s += __shfl_xor(s, 32, 64); qq += __shfl_xor(qq, 32, 64);
    if (lane < 16){
      atomicAdd(&repl[r_idx*256 + nt*16 + lane], s);
      atomicAdd(&repl[r_idx*256 + 128 + nt*16 + lane], qq);
    }
  }
}
template<int ST>
static __device__ __forceinline__ void dumpC(f32x4_t acc[4][4], unsigned short* Cw,
                                             int c15, int q){
  #pragma unroll
  for (int mt = 0; mt < 4; mt++)
    #pragma unroll
    for (int nt = 0; nt < 4; nt++){
      #pragma unroll
      for (int r = 0; r < 4; r++){
        int row = mt*16 + q*4 + r;
        Cw[row*ST + nt*16 + c15] = f2bf(acc[mt][nt][r]);
      }
    }
}
// segmented raw min/max over bucket-ordered tile; lane = channel
template<int ST>
static __device__ __forceinline__ void seg_walk(const unsigned short* Cw, const int* nodes,
                                                long tb, int E, int lane,
                                                unsigned* __restrict__ tmax,
                                                unsigned* __restrict__ tmin){
  long rem = (long)E - tb;
  int limit = rem >= 64 ? 64 : (rem > 0 ? (int)rem : 0);
  if (limit <= 0) return;
  int cur = nodes[0];
  float mx = -3.4e38f, mn = 3.4e38f;
  for (int k = 0; k < limit; k++){
    int nd = nodes[k];
    float v = bf2f(Cw[k*ST + lane]);
    if (nd != cur){
      atomicMax(&tmax[(size_t)cur*64 + lane], ordf(mx));
      atomicMin(&tmin[(size_t)cur*64 + lane], ordf(mn));
      cur = nd; mx = v; mn = v;
    } else {
      mx = fmaxf(mx, v); mn = fminf(mn, v);
    }
  }
  atomicMax(&tmax[(size_t)cur*64 + lane], ordf(mx));
  atomicMin(&tmin[(size_t)cur*64 + lane], ordf(mn));
}
// stage z1 (BN1+ReLU of m1 from pos) into A row
static __device__ __forceinline__ void stage_z1(const float* __restrict__ pos,
                                                const void* __restrict__ ei,
                                                long e_src, long e_dst, int N,
                                                const float* __restrict__ W1,
                                                const float* __restrict__ b1,
                                                const float* __restrict__ ss1,
                                                int m64, unsigned short* Ar){
  int si = clampi(ld_idx(ei, e_src, m64), 0, N-1);
  int di = clampi(ld_idx(ei, e_dst, m64), 0, N-1);
  float x0 = pos[di*3+0], x1 = pos[di*3+1], x2 = pos[di*3+2];
  float j0 = pos[si*3+0]-x0, j1 = pos[si*3+1]-x1, j2 = pos[si*3+2]-x2;
  #pragma unroll
  for (int c4 = 0; c4 < 64; c4 += 4){
    unsigned short h[4];
    #pragma unroll
    for (int u = 0; u < 4; u++){
      int c = c4 + u;
      float m = b1[c];
      m = fmaf(x0, W1[c*6+0], m); m = fmaf(x1, W1[c*6+1], m); m = fmaf(x2, W1[c*6+2], m);
      m = fmaf(j0, W1[c*6+3], m); m = fmaf(j1, W1[c*6+4], m); m = fmaf(j2, W1[c*6+5], m);
      h[u] = f2bf(fmaxf(fmaf(m, ss1[c], ss1[64 + c]), 0.f));
    }
    uint2 pk;
    pk.x = ((unsigned)h[1] << 16) | h[0];
    pk.y = ((unsigned)h[3] << 16) | h[2];
    *(uint2*)&Ar[c4] = pk;
  }
}

// ---------- m2 stats only (natural edge order) ----------
__global__ void __launch_bounds__(128, 1)
k_m2stats(const float* __restrict__ pos, const void* __restrict__ ei,
          int E, int N, const int* dmode,
          const float* __restrict__ W1, const float* __restrict__ b1,
          const float* __restrict__ ss1,
          const float* __restrict__ W2, const float* __restrict__ b2,
          float* __restrict__ repl){
  __shared__ unsigned short A[2][64][72];
  int m64 = dmode[0];
  int wv = threadIdx.x >> 6, lane = threadIdx.x & 63;
  long tb = (long)blockIdx.x*128 + wv*64;
  long e = tb + lane;
  unsigned short* Ar = &A[wv][lane][0];
  if (e < E){
    stage_z1(pos, ei, e, (long)E + e, N, W1, b1, ss1, m64, Ar);
  } else {
    #pragma unroll
    for (int c4 = 0; c4 < 64; c4 += 4) *(uint2*)&Ar[c4] = make_uint2(0u, 0u);
  }
  __syncthreads();
  int c15 = lane & 15, q = lane >> 4;
  short8_t bf[4][2];
  loadB<2>(W2, c15, q, bf);
  f32x4_t acc[4][4];
  do_mfma<2, 72>(&A[wv][0][0], bf, b2, c15, q, acc);
  stats_acc(acc, tb, E, lane, q, (blockIdx.x*2 + wv) & 63, repl);
}

// ---------- conv1 fused: z1 -> m2 -> bn2relu -> m3 -> stats + raw min/max agg ----------
__global__ void __launch_bounds__(128, 1)
k_conv1f(const float* __restrict__ pos, const void* __restrict__ ei,
         const int* __restrict__ bucket, const int* __restrict__ nodeof,
         int E, int N, const int* dmode,
         const float* __restrict__ W1, const float* __restrict__ b1,
         const float* __restrict__ ss1, const float* __restrict__ ss2,
         const float* __restrict__ W2, const float* __restrict__ b2,
         const float* __restrict__ W3, const float* __restrict__ b3,
         float* __restrict__ repl, unsigned* __restrict__ tmax, unsigned* __restrict__ tmin){
  __shared__ unsigned short A[2][64][72];
  __shared__ int nds[2][64];
  int m64 = dmode[0];
  int wv = threadIdx.x >> 6, lane = threadIdx.x & 63;
  long tb = (long)blockIdx.x*128 + wv*64;
  long t = tb + lane;
  unsigned short* Ar = &A[wv][lane][0];
  if (t < E){
    int p = bucket[t];
    nds[wv][lane] = nodeof[t];
    stage_z1(pos, ei, (long)p, (long)E + p, N, W1, b1, ss1, m64, Ar);
  } else {
    nds[wv][lane] = 0;
    #pragma unroll
    for (int c4 = 0; c4 < 64; c4 += 4) *(uint2*)&Ar[c4] = make_uint2(0u, 0u);
  }
  __syncthreads();
  int c15 = lane & 15, q = lane >> 4;
  unsigned short* Aw = &A[wv][0][0];
  f32x4_t acc[4][4];
  {
    short8_t bf[4][2];
    loadB<2>(W2, c15, q, bf);
    do_mfma<2, 72>(Aw, bf, b2, c15, q, acc);
  }
  // BN2 + ReLU in C layout (channel = nt*16 + c15)
  #pragma unroll
  for (int nt = 0; nt < 4; nt++){
    int ch = nt*16 + c15;
    float sc = ss2[ch], sh = ss2[64 + ch];
    #pragma unroll
    for (int mt = 0; mt < 4; mt++)
      #pragma unroll
      for (int r = 0; r < 4; r++)
        acc[mt][nt][r] = fmaxf(fmaf(acc[mt][nt][r], sc, sh), 0.f);
  }
  __syncthreads();                 // all waves done reading z1
  dumpC<72>(acc, Aw, c15, q);      // z2 row-major
  __syncthreads();
  {
    short8_t bf[4][2];
    loadB<2>(W3, c15, q, bf);
    do_mfma<2, 72>(Aw, bf, b3, c15, q, acc);   // m3
  }
  stats_acc(acc, tb, E, lane, q, (blockIdx.x*2 + wv) & 63, repl);
  __syncthreads();
  dumpC<72>(acc, Aw, c15, q);      // m3 row-major bf16
  __syncthreads();
  seg_walk<72>(Aw, &nds[wv][0], tb, E, lane, tmax, tmin);
}

// ---------- conv2 fused: m4 = [xi|xj]@Wab + stats + raw min/max agg ----------
__global__ void __launch_bounds__(128, 1)
k_conv2f(const unsigned short* __restrict__ x1, const void* __restrict__ ei,
         const int* __restrict__ bucket, const int* __restrict__ nodeof,
         int E, int N, const int* dmode,
         const float* __restrict__ Wab, const float* __restrict__ b4,
         float* __restrict__ repl, unsigned* __restrict__ tmax, unsigned* __restrict__ tmin){
  __shared__ unsigned short A[2][64][136];
  __shared__ int nds[2][64];
  int m64 = dmode[0];
  int wv = threadIdx.x >> 6, lane = threadIdx.x & 63;
  long tb = (long)blockIdx.x*128 + wv*64;
  long t = tb + lane;
  unsigned short* Ar = &A[wv][lane][0];
  if (t < E){
    int p = bucket[t];
    nds[wv][lane] = nodeof[t];
    int si = clampi(ld_idx(ei, (long)p, m64), 0, N-1);
    int di = clampi(ld_idx(ei, (long)E + p, m64), 0, N-1);
    const uint4* xi4 = (const uint4*)(x1 + (size_t)di*64);
    const uint4* xj4 = (const uint4*)(x1 + (size_t)si*64);
    #pragma unroll
    for (int k = 0; k < 8; k++) *(uint4*)&Ar[k*8]      = xi4[k];
    #pragma unroll
    for (int k = 0; k < 8; k++) *(uint4*)&Ar[64 + k*8] = xj4[k];
  } else {
    nds[wv][lane] = 0;
    #pragma unroll
    for (int k = 0; k < 16; k++) *(uint4*)&Ar[k*8] = make_uint4(0u,0u,0u,0u);
  }
  __syncthreads();
  int c15 = lane & 15, q = lane >> 4;
  unsigned short* Aw = &A[wv][0][0];
  f32x4_t acc[4][4];
  {
    short8_t bf[4][4];
    loadB<4>(Wab, c15, q, bf);
    do_mfma<4, 136>(Aw, bf, b4, c15, q, acc);
  }
  stats_acc(acc, tb, E, lane, q, (blockIdx.x*2 + wv) & 63, repl);
  __syncthreads();
  dumpC<136>(acc, Aw, c15, q);
  __syncthreads();
  seg_walk<136>(Aw, &nds[wv][0], tb, E, lane, tmax, tmin);
}

// ---------- apply BN post-aggregation: x[n][c] = relu(sc>=0 ? bn(max) : bn(min)) ----------
__global__ void k_applybn(const unsigned* __restrict__ tmax, const unsigned* __restrict__ tmin,
                          const float* __restrict__ ss, long total,
                          unsigned short* __restrict__ xout){
  long i = (long)blockIdx.x*256 + threadIdx.x;
  if (i >= total) return;
  int c = (int)(i & 63);
  unsigned um = tmax[i];
  float out = 0.f;
  if (um != 0u){
    float sc = ss[c], sh = ss[64 + c];
    float v = (sc >= 0.f) ? iordf(um) : iordf(tmin[i]);
    out = fmaxf(fmaf(v, sc, sh), 0.f);
  }
  xout[i] = f2bf(out);
}

// ---------- lin5 (MFMA): y5 = cat(x1,x2)@W5^T + b5, fused BN5 stats ----------
__global__ void __launch_bounds__(128, 1)
k_lin5m(const unsigned short* __restrict__ x1, const unsigned short* __restrict__ x2,
        int N, const float* __restrict__ W5, const float* __restrict__ b5,
        unsigned short* __restrict__ y5, float* __restrict__ repl){
  __shared__ unsigned short A[2][64][136];
  __shared__ unsigned short Cb[2][64][72];
  int wv = threadIdx.x >> 6, lane = threadIdx.x & 63;
  long nb0 = (long)blockIdx.x*128 + wv*64;
  long n = nb0 + lane;
  unsigned short* Ar = &A[wv][lane][0];
  if (n < N){
    const uint4* a4 = (const uint4*)(x1 + (size_t)n*64);
    const uint4* b4 = (const uint4*)(x2 + (size_t)n*64);
    #pragma unroll
    for (int k = 0; k < 8; k++) *(uint4*)&Ar[k*8]      = a4[k];
    #pragma unroll
    for (int k = 0; k < 8; k++) *(uint4*)&Ar[64 + k*8] = b4[k];
  } else {
    #pragma unroll
    for (int k = 0; k < 16; k++) *(uint4*)&Ar[k*8] = make_uint4(0u,0u,0u,0u);
  }
  __syncthreads();
  int c15 = lane & 15, q = lane >> 4;
  int r_idx = (blockIdx.x*2 + wv) & 63;
  unsigned short* Aw = &A[wv][0][0];
  unsigned short* Cw = &Cb[wv][0][0];
  for (int h = 0; h < 2; h++){
    const float* Wp = W5 + (size_t)h*64*128;
    short8_t bf[4][4];
    loadB<4>(Wp, c15, q, bf);
    f32x4_t acc[4][4];
    do_mfma<4, 136>(Aw, bf, b5 + h*64, c15, q, acc);
    stats_acc(acc, nb0, N, lane, q, r_idx, repl + 0);   // channels offset handled below
    // NOTE: stats_acc writes channels [0,64) of repl row; shift for h=1 done via pointer:
    // (handled by calling with repl and channel offset) -- see below custom:
    if (h == 1){
      // stats_acc above wrote to wrong channel block for h=1; compensate:
      // (we instead inline correct commit here -- so undo is not possible)
    }
    dumpC<72>(acc, Cw, c15, q);
    int rl = lane >> 3, ch8 = lane & 7;
    #pragma unroll
    for (int pass = 0; pass < 8; pass++){
      int row = pass*8 + rl;
      long nn = nb0 + row;
      if (nn < N)
        *(uint4*)(y5 + (size_t)nn*128 + h*64 + ch8*8) = *(const uint4*)&Cw[row*72 + ch8*8];
    }
    __syncthreads();
  }
}

// correction kernel-free approach: k_lin5m above must commit stats to the right
// channel half. To keep this simple and correct, stats for lin5 are recomputed
// here from y5 (N x 128 bf16, sequential, cheap) instead of fused:
__global__ void k_stats_bf16(const unsigned short* __restrict__ buf, long total, int cmask,
                             float* __restrict__ repl){
  int tid = blockIdx.x*256 + threadIdx.x;
  int c = tid & cmask;
  long stride = (long)gridDim.x * 256;
  float s = 0.f, q = 0.f;
  long i = tid;
  for (; i + 3*stride < total; i += 4*stride){
    float v0 = bf2f(buf[i]);
    float v1 = bf2f(buf[i +   stride]);
    float v2 = bf2f(buf[i + 2*stride]);
    float v3 = bf2f(buf[i + 3*stride]);
    s += (v0 + v1) + (v2 + v3);
    q += (v0*v0 + v1*v1) + (v2*v2 + v3*v3);
  }
  for (; i < total; i += stride){ float v = bf2f(buf[i]); s += v; q += v*v; }
  int r = (tid >> 6) & 63;
  atomicAdd(&repl[r*256 + c], s);
  atomicAdd(&repl[r*256 + 128 + c], q);
}

// ---------- pool ----------
__global__ void k_pool(const unsigned short* __restrict__ y5, const void* __restrict__ batch, int N,
                       const int* dmode, const float* __restrict__ ss5, unsigned int* __restrict__ pooled){
  int m64 = dmode[0];
  int c = threadIdx.x & 127;
  int par = threadIdx.x >> 7;
  int n0 = blockIdx.x*128;
  int n1 = min(n0 + 128, N);
  float sc = ss5[c], sh = ss5[128 + c];
  int curb = -1; float curm = 0.f;
  for (int n = n0 + par; n < n1; n += 2){
    int b = clampi(ld_idx(batch, (long)n, m64), 0, 63);
    float v = fmaf(bf2f(y5[(size_t)n*128 + c]), sc, sh);
    if (b != curb){
      if (curb >= 0) atomicMax(&pooled[curb*128 + c], __float_as_uint(fmaxf(curm, 0.f)));
      curb = b; curm = v;
    } else {
      curm = fmaxf(curm, v);
    }
  }
  if (curb >= 0) atomicMax(&pooled[curb*128 + c], __float_as_uint(fmaxf(curm, 0.f)));
}

// ---------- head ----------
__global__ void k_pooled2f(const unsigned int* __restrict__ pooled, float* __restrict__ pf){
  int i = blockIdx.x*256 + threadIdx.x;
  if (i < 8192) pf[i] = __uint_as_float(pooled[i]);
}

__global__ void k_linH(const float* __restrict__ X, const float* __restrict__ W,
                       const float* __restrict__ b, int CI, int CO, float* __restrict__ Y){
  int cell = blockIdx.x*256 + threadIdx.x;
  if (cell >= 64*CO) return;
  int r = cell / CO, c = cell - r*CO;
  const float* xr = X + r*CI;
  const float* wr = W + c*CI;
  float a = b[c];
  for (int j = 0; j < CI; j++) a = fmaf(xr[j], wr[j], a);
  Y[cell] = a;
}

__global__ void k_bnH(const float* __restrict__ Y, int CO,
                      const float* __restrict__ g, const float* __restrict__ be,
                      float* __restrict__ ss){
  int c = threadIdx.x;
  if (c >= CO) return;
  float s = 0.f;
  for (int r = 0; r < 64; r++) s += Y[r*CO + c];
  float mean = s * (1.f/64.f);
  float q = 0.f;
  for (int r = 0; r < 64; r++){ float d = Y[r*CO + c] - mean; q += d*d; }
  float var = fmaxf(q * (1.f/64.f), 0.f);
  float inv = rsqrtf(var + EPS_BN);
  float sc = g[c] * inv;
  ss[c] = sc;
  ss[CO + c] = be[c] - mean*sc;
}

__global__ void k_bnreluH(float* __restrict__ Y, int CO, const float* __restrict__ ss){
  int cell = blockIdx.x*256 + threadIdx.x;
  if (cell >= 64*CO) return;
  int c = cell % CO;
  Y[cell] = fmaxf(fmaf(Y[cell], ss[c], ss[CO + c]), 0.f);
}

__global__ void k_logsm(const float* __restrict__ Z, float* __restrict__ out){
  int r = threadIdx.x;   // 64 threads
  const float* zr = Z + r*40;
  float m = zr[0];
  for (int c = 1; c < 40; c++) m = fmaxf(m, zr[c]);
  float s = 0.f;
  for (int c = 0; c < 40; c++) s += expf(zr[c] - m);
  float ls = logf(s);
  for (int c = 0; c < 40; c++) out[r*40 + c] = zr[c] - m - ls;
}

// ---------- launch ----------
extern "C" void kernel_launch(void* const* d_in, const int* in_sizes, int n_in,
                              void* d_out, int out_size, void* d_ws, size_t ws_size,
                              hipStream_t stream) {
  const void* pos   = d_in[0];
  const void* ei    = d_in[1];
  const void* batch = d_in[2];
  (void)n_in;

  const int N = in_sizes[0] / 3;
  const int E = in_sizes[1] / 2;

  // ---- workspace layout ----
  auto al = [](size_t x){ return (x + 255) & ~(size_t)255; };
  char* w = (char*)d_ws;
  size_t o = 0;
  float* repl = (float*)(w + o);                 o += (size_t)64*256*4;
  unsigned int* pooled = (unsigned int*)(w + o); o += (size_t)64*128*4;
  int* deg = (int*)(w + o);                      o += al((size_t)4*N);
  size_t zero_bytes = o;
  // raw-aggregation buffers: tmax pair (memset 0x00), tmin pair (memset 0xFF)
  unsigned* tmaxA = (unsigned*)(w + o);          o += (size_t)64*N*4;
  unsigned* tmaxB = (unsigned*)(w + o);          o += (size_t)64*N*4;
  size_t tmax_bytes = (size_t)64*N*4*2;
  unsigned* tminA = (unsigned*)(w + o);          o += (size_t)64*N*4;
  unsigned* tminB = (unsigned*)(w + o);          o += (size_t)64*N*4;
  size_t tmin_bytes = (size_t)64*N*4*2;
  int* dmode = (int*)(w + o);                    o += 256;
  int* offs = (int*)(w + o);                     o += al((size_t)4*(N + 1));
  int* cursor = (int*)(w + o);                   o += al((size_t)4*N);
  int* part = (int*)(w + o);                     o += 4096;
  int* bucket = (int*)(w + o);                   o += al((size_t)4*E);
  int* nodeof = (int*)(w + o);                   o += al((size_t)4*E);
  float* ss1 = (float*)(w + o);                  o += 1024;
  float* ss2 = (float*)(w + o);                  o += 1024;
  float* ss3 = (float*)(w + o);                  o += 1024;
  float* ss4 = (float*)(w + o);                  o += 1024;
  float* ss5 = (float*)(w + o);                  o += 1024;
  float* ssH = (float*)(w + o);                  o += 1024;
  float* Wab = (float*)(w + o);                  o += (size_t)8192*4;
  float* pooledF = (float*)(w + o);              o += (size_t)8192*4;
  float* Y6 = (float*)(w + o);                   o += (size_t)8192*4;
  float* Y7 = (float*)(w + o);                   o += (size_t)8192*4;
  float* Zl = (float*)(w + o);                   o += al((size_t)2560*4);
  // fp32 expansion region
  float* expBase = (float*)(w + o);
  float* ep = expBase;
  float* epos = ep; ep += (size_t)3*N;
  float* eW[9], *eb[9], *eg[9], *ebe[9];
  const int wsz[9] = {0, 64*6, 64*64, 64*64, 64*128, 128*128, 128*128, 128*128, 40*128};
  const int bsz[9] = {0, 64, 64, 64, 64, 128, 128, 128, 40};
  for (int i = 1; i <= 8; i++){
    eW[i] = ep; ep += wsz[i];
    eb[i] = ep; ep += bsz[i];
    if (i < 8){ eg[i] = ep; ep += bsz[i]; ebe[i] = ep; ep += bsz[i]; }
  }
  long expCount = (long)(ep - expBase);
  o += al((size_t)expCount * 4);
  unsigned short* x1b = (unsigned short*)(w + o); o += al((size_t)2*64*N);
  unsigned short* x2b = (unsigned short*)(w + o); o += al((size_t)2*64*N);
  unsigned short* y5b = (unsigned short*)(w + o); o += al((size_t)2*128*N);

  float* out_f = (float*)d_out;
  if (ws_size < o){
    k_sentinel<<<cdiv(out_size,256), 256, 0, stream>>>(out_f, out_size);
    return;
  }

  hipMemsetAsync(w, 0, zero_bytes, stream);
  hipMemsetAsync(tmaxA, 0x00, tmax_bytes, stream);
  hipMemsetAsync(tminA, 0xFF, tmin_bytes, stream);
  k_detect<<<1, 256, 0, stream>>>(ei, pos, dmode);

  // expand all float inputs -> fp32
  ExpArgs ea;
  int it = 0;
  ea.it[it++] = {pos, epos, 3*N};
  int di_idx = 3;
  for (int i = 1; i <= 8; i++){
    ea.it[it++] = {d_in[di_idx++], eW[i], wsz[i]};
    ea.it[it++] = {d_in[di_idx++], eb[i], bsz[i]};
    if (i < 8){
      ea.it[it++] = {d_in[di_idx++], eg[i], bsz[i]};
      ea.it[it++] = {d_in[di_idx++], ebe[i], bsz[i]};
    }
  }
  k_expand<<<dim3(cdiv(3*N,256), 31), 256, 0, stream>>>(ea, it, dmode);
  k_prepW4<<<32, 256, 0, stream>>>(eW[4], Wab);

  const int nb = cdiv(N, 1024);
  // CSR build
  k_hist<<<cdiv(E,256), 256, 0, stream>>>(ei, E, N, dmode, deg);
  k_scan1<<<nb, 1024, 0, stream>>>(deg, N, offs, part);
  k_scan2<<<1, 1024, 0, stream>>>(part, nb);
  k_scan3<<<nb, 1024, 0, stream>>>(deg, part, N, E, offs, cursor);
  k_fill<<<cdiv(E,256), 256, 0, stream>>>(ei, E, N, dmode, cursor, bucket, nodeof);

  // conv1: m1 stats -> m2 stats -> fused (m2 recompute, bn2relu, m3, stats, raw agg)
  k_m1stats<<<cdiv(E,2048), 256, 0, stream>>>(epos, ei, E, N, dmode, eW[1], eb[1], repl);
  k_finalize<<<1, 128, 0, stream>>>(repl, 64, (float)E, eg[1], ebe[1], ss1);
  k_m2stats<<<cdiv(E,128), 128, 0, stream>>>(epos, ei, E, N, dmode, eW[1], eb[1], ss1,
                                             eW[2], eb[2], repl);
  k_finalize<<<1, 128, 0, stream>>>(repl, 64, (float)E, eg[2], ebe[2], ss2);
  k_conv1f<<<cdiv(E,128), 128, 0, stream>>>(epos, ei, bucket, nodeof, E, N, dmode,
                                            eW[1], eb[1], ss1, ss2, eW[2], eb[2],
                                            eW[3], eb[3], repl, tmaxA, tminA);
  k_finalize<<<1, 128, 0, stream>>>(repl, 64, (float)E, eg[3], ebe[3], ss3);
  k_applybn<<<cdiv(N*64,256), 256, 0, stream>>>(tmaxA, tminA, ss3, (long)N*64, x1b);

  // conv2 fused
  k_conv2f<<<cdiv(E,128), 128, 0, stream>>>(x1b, ei, bucket, nodeof, E, N, dmode,
                                            Wab, eb[4], repl, tmaxB, tminB);
  k_finalize<<<1, 128, 0, stream>>>(repl, 64, (float)E, eg[4], ebe[4], ss4);
  k_applybn<<<cdiv(N*64,256), 256, 0, stream>>>(tmaxB, tminB, ss4, (long)N*64, x2b);

  // lin5 (MFMA) + BN5 stats (separate pass over y5) + pool
  k_lin5m<<<cdiv(N,128), 128, 0, stream>>>(x1b, x2b, N, eW[5], eb[5], y5b, repl);
  // clear stats contaminated by lin5m's fused path (it wrote only channel block [0,64)
  // for both halves); recompute cleanly from y5:
  k_finalize<<<1, 128, 0, stream>>>(repl, 128, 1.0f, eg[5], ebe[5], ss5);  // drain repl to zero
  k_stats_bf16<<<512, 256, 0, stream>>>(y5b, (long)N*128, 127, repl);
  k_finalize<<<1, 128, 0, stream>>>(repl, 128, (float)N, eg[5], ebe[5], ss5);
  k_pool<<<cdiv(N,128), 256, 0, stream>>>(y5b, batch, N, dmode, ss5, pooled);

  // head
  k_pooled2f<<<32, 256, 0, stream>>>(pooled, pooledF);
  k_linH<<<32, 256, 0, stream>>>(pooledF, eW[6], eb[6], 128, 128, Y6);
  k_bnH<<<1, 128, 0, stream>>>(Y6, 128, eg[6], ebe[6], ssH);
  k_bnreluH<<<32, 256, 0, stream>>>(Y6, 128, ssH);
  k_linH<<<32, 256, 0, stream>>>(Y6, eW[7], eb[7], 128, 128, Y7);
  k_bnH<<<1, 128, 0, stream>>>(Y7, 128, eg[7], ebe[7], ssH);
  k_bnreluH<<<32, 256, 0, stream>>>(Y7, 128, ssH);
  k_linH<<<10, 256, 0, stream>>>(Y7, eW[8], eb[8], 128, 40, Zl);
  k_logsm<<<1, 64, 0, stream>>>(Zl, out_f);
}

// Round 16
// 1016.118 us; speedup vs baseline: 1.0762x; 1.0762x over previous
//
#include <hip/hip_runtime.h>
#include <hip/hip_bf16.h>
#include <math.h>

#define EPS_BN 1e-5f

// Wire formats: float inputs bf16 (runtime-detected), ints int32/int64 (detected), OUTPUT FP32.
// r12: MFMA convs. r13: MFMA lin5. r14: pool re-grid. r15: mbuf eliminated via
// raw-min/max aggregation + post-pool BN. r16: packed v_cvt_pk_bf16_f32 for all
// hot fp32->bf16 conversions (was ~800 VALU ops/thread, 48% VALUBusy in conv1f);
// lin5 fused stats fixed (channel offset) -> drain + stats pass removed.

typedef short short8_t __attribute__((ext_vector_type(8)));
typedef float f32x4_t  __attribute__((ext_vector_type(4)));

// ---------- helpers ----------
static __device__ __forceinline__ float bf2f(unsigned short b){
  return __uint_as_float(((unsigned)b) << 16);
}
static __device__ __forceinline__ unsigned short f2bf(float f){
  unsigned u = __float_as_uint(f);
  u += 0x7fffu + ((u >> 16) & 1u);   // RNE (finite values only)
  return (unsigned short)(u >> 16);
}
// packed RNE via v_cvt_pk_bf16_f32 (1 instr / 2 values)
static __device__ __forceinline__ unsigned pk2(float a, float b){
  __hip_bfloat162 t = __float22bfloat162_rn(make_float2(a, b));
  return *(unsigned*)&t;
}
static inline int cdiv(int a, int b){ return (a + b - 1) / b; }
static __device__ __forceinline__ int clampi(int v, int lo, int hi){
  return v < lo ? lo : (v > hi ? hi : v);
}
static __device__ __forceinline__ int ld_idx(const void* p, long e, int m64){
  return m64 ? (int)((const long long*)p)[e] : ((const int*)p)[e];
}
// order-preserving float<->uint
static __device__ __forceinline__ unsigned ordf(float f){
  unsigned b = __float_as_uint(f);
  return (b & 0x80000000u) ? ~b : (b | 0x80000000u);
}
static __device__ __forceinline__ float iordf(unsigned u){
  unsigned b = (u & 0x80000000u) ? (u & 0x7FFFFFFFu) : ~u;
  return __uint_as_float(b);
}

// ---------- sentinel ----------
__global__ void k_sentinel(float* out, int n){
  int i = blockIdx.x*256 + threadIdx.x;
  if (i < n) out[i] = -12288.0f;
}

// ---------- runtime dtype detection ----------
__global__ void k_detect(const void* ei, const void* pos, int* dmode){
  __shared__ int nz, ff;
  if (threadIdx.x == 0){ nz = 0; ff = 0; }
  __syncthreads();
  const int* w32 = (const int*)ei;
  if (w32[1 + 2*threadIdx.x] != 0) nz = 1;
  const unsigned short* ph = (const unsigned short*)pos;
  int bad = 0;
  for (int i = threadIdx.x; i < 8192; i += 256)
    if (((ph[i] >> 7) & 0xFF) == 0xFF) bad = 1;
  if (bad) ff = 1;
  __syncthreads();
  if (threadIdx.x == 0){ dmode[0] = nz ? 0 : 1; dmode[1] = ff; }
}

// ---------- expand float inputs -> fp32 scratch ----------
struct ExpItem { const void* s; float* d; int n; };
struct ExpArgs { ExpItem it[31]; };
__global__ void k_expand(ExpArgs a, int cnt, const int* dmode){
  int i = blockIdx.y;
  if (i >= cnt) return;
  int m32 = dmode[1];
  int t = blockIdx.x*256 + threadIdx.x;
  if (t < a.it[i].n){
    a.it[i].d[t] = m32 ? ((const float*)a.it[i].s)[t]
                       : bf2f(((const unsigned short*)a.it[i].s)[t]);
  }
}

// ---------- Wab prep ----------
__global__ void k_prepW4(const float* __restrict__ W4, float* __restrict__ Wab){
  int i = blockIdx.x*256 + threadIdx.x;
  if (i < 8192){
    int c = i >> 7, k = i & 127;
    float v;
    if (k < 64) v = W4[c*128 + k] - W4[c*128 + 64 + k];
    else        v = W4[c*128 + k];
    Wab[i] = v;
  }
}

// ---------- CSR build ----------
__global__ void k_hist(const void* __restrict__ ei, int E, int N, const int* dmode, int* __restrict__ deg){
  int m64 = dmode[0];
  int e = blockIdx.x*256 + threadIdx.x;
  if (e < E) atomicAdd(&deg[clampi(ld_idx(ei, (long)E + e, m64), 0, N-1)], 1);
}

__global__ void k_scan1(const int* __restrict__ deg, int N, int* __restrict__ incl, int* __restrict__ part){
  __shared__ int s[1024];
  int i = blockIdx.x*1024 + threadIdx.x;
  s[threadIdx.x] = (i < N) ? deg[i] : 0;
  __syncthreads();
  for (int off = 1; off < 1024; off <<= 1){
    int t = (threadIdx.x >= off) ? s[threadIdx.x - off] : 0;
    __syncthreads();
    s[threadIdx.x] += t;
    __syncthreads();
  }
  if (i < N) incl[i] = s[threadIdx.x];
  if (threadIdx.x == 1023) part[blockIdx.x] = s[1023];
}

__global__ void k_scan2(int* __restrict__ part, int nb){
  __shared__ int s[1024];
  int i = threadIdx.x;
  s[i] = (i < nb) ? part[i] : 0;
  __syncthreads();
  for (int off = 1; off < 1024; off <<= 1){
    int t = (i >= off) ? s[i - off] : 0;
    __syncthreads();
    s[i] += t;
    __syncthreads();
  }
  if (i < nb) part[i] = s[i];
}

__global__ void k_scan3(const int* __restrict__ deg, const int* __restrict__ part, int N, int E,
                        int* __restrict__ offs, int* __restrict__ cursor){
  int i = blockIdx.x*1024 + threadIdx.x;
  if (i < N){
    int prev = (blockIdx.x > 0) ? part[blockIdx.x - 1] : 0;
    int v = prev + offs[i] - deg[i];
    offs[i] = v;
    cursor[i] = v;
  }
  if (blockIdx.x == 0 && threadIdx.x == 0) offs[N] = E;
}

__global__ void k_fill(const void* __restrict__ ei, int E, int N, const int* dmode,
                       int* __restrict__ cursor, int* __restrict__ bucket, int* __restrict__ nodeof){
  int m64 = dmode[0];
  int e = blockIdx.x*256 + threadIdx.x;
  if (e < E){
    int nd = clampi(ld_idx(ei, (long)E + e, m64), 0, N-1);
    int p = atomicAdd(&cursor[nd], 1);
    if (p >= 0 && p < E){ bucket[p] = e; nodeof[p] = nd; }
  }
}

// ---------- conv1 layer1 stats ----------
__global__ void __launch_bounds__(256, 1)
k_m1stats(const float* __restrict__ pos, const void* __restrict__ ei,
          int E, int N, const int* dmode,
          const float* __restrict__ W1, const float* __restrict__ b1,
          float* __restrict__ repl){
  int m64 = dmode[0];
  int lane = threadIdx.x & 63;
  int flatwave = (blockIdx.x*256 + threadIdx.x) >> 6;
  long base = (long)flatwave * 512;
  float as[64], aq[64];
  #pragma unroll
  for (int c = 0; c < 64; c++){ as[c] = 0.f; aq[c] = 0.f; }
  for (int k = 0; k < 8; k++){
    long e = base + (long)k*64 + lane;
    if (e < E){
      int si = clampi(ld_idx(ei, e, m64), 0, N-1);
      int di = clampi(ld_idx(ei, (long)E + e, m64), 0, N-1);
      float x0 = pos[di*3+0], x1 = pos[di*3+1], x2 = pos[di*3+2];
      float j0 = pos[si*3+0]-x0, j1 = pos[si*3+1]-x1, j2 = pos[si*3+2]-x2;
      #pragma unroll
      for (int c = 0; c < 64; c++){
        float m = b1[c];
        m = fmaf(x0, W1[c*6+0], m); m = fmaf(x1, W1[c*6+1], m); m = fmaf(x2, W1[c*6+2], m);
        m = fmaf(j0, W1[c*6+3], m); m = fmaf(j1, W1[c*6+4], m); m = fmaf(j2, W1[c*6+5], m);
        as[c] += m; aq[c] += m*m;
      }
    }
  }
  float outs = 0.f, outq = 0.f;
  #pragma unroll
  for (int c = 0; c < 64; c++){
    float s = as[c], q = aq[c];
    #pragma unroll
    for (int m = 1; m < 64; m <<= 1){ s += __shfl_xor(s, m, 64); q += __shfl_xor(q, m, 64); }
    if (lane == c){ outs = s; outq = q; }
  }
  int r = flatwave & 63;
  atomicAdd(&repl[r*256 + lane], outs);
  atomicAdd(&repl[r*256 + 128 + lane], outq);
}

// ---------- finalize BN ----------
__global__ void k_finalize(float* __restrict__ repl, int C, float count,
                           const float* __restrict__ g, const float* __restrict__ be,
                           float* __restrict__ ss){
  int c = threadIdx.x;
  if (c < C){
    float s = 0.f, q = 0.f;
    for (int r = 0; r < 64; r++){
      s += repl[r*256 + c];       repl[r*256 + c] = 0.f;
      q += repl[r*256 + 128 + c]; repl[r*256 + 128 + c] = 0.f;
    }
    float mean = s / count;
    float var  = fmaxf(q / count - mean*mean, 0.f);
    float inv  = rsqrtf(var + EPS_BN);
    float sc   = g[c] * inv;
    ss[c]     = sc;
    ss[C + c] = be[c] - mean*sc;
  }
}

// ---------- MFMA building blocks ----------
// A layout (m120): lane holds A[m=lane&15][k=(lane>>4)*8+j]
// C/D layout (m89/m91): col=lane&15, row=(lane>>4)*4+reg
template<int KT>
static __device__ __forceinline__ void loadB(const float* __restrict__ Wp, int c15, int q,
                                             short8_t bf[4][KT]){
  #pragma unroll
  for (int nt = 0; nt < 4; nt++){
    int c = nt*16 + c15;
    #pragma unroll
    for (int kt = 0; kt < KT; kt++){
      const float* wr = Wp + (size_t)c*(KT*32) + kt*32 + q*8;
      union { short8_t v; unsigned u[4]; } pb;
      #pragma unroll
      for (int j = 0; j < 4; j++) pb.u[j] = pk2(wr[2*j], wr[2*j+1]);
      bf[nt][kt] = pb.v;
    }
  }
}
template<int KT, int ST>
static __device__ __forceinline__ void do_mfma(const unsigned short* Aw, short8_t bf[4][KT],
                                               const float* __restrict__ bias, int c15, int q,
                                               f32x4_t acc[4][4]){
  #pragma unroll
  for (int mt = 0; mt < 4; mt++)
    #pragma unroll
    for (int nt = 0; nt < 4; nt++){
      float bv = bias[nt*16 + c15];
      acc[mt][nt] = (f32x4_t){bv, bv, bv, bv};
    }
  #pragma unroll
  for (int mt = 0; mt < 4; mt++){
    #pragma unroll
    for (int kt = 0; kt < KT; kt++){
      short8_t af = *(const short8_t*)&Aw[(mt*16 + c15)*ST + kt*32 + q*8];
      #pragma unroll
      for (int nt = 0; nt < 4; nt++)
        acc[mt][nt] = __builtin_amdgcn_mfma_f32_16x16x32_bf16(af, bf[nt][kt], acc[mt][nt], 0, 0, 0);
    }
  }
}
// stats commit with channel offset (choff) into repl row [choff..choff+64)
static __device__ __forceinline__ void stats_acc(f32x4_t acc[4][4], long tb, int E,
                                                 int lane, int q, int r_idx, int choff,
                                                 float* __restrict__ repl){
  #pragma unroll
  for (int nt = 0; nt < 4; nt++){
    float s = 0.f, qq = 0.f;
    #pragma unroll
    for (int mt = 0; mt < 4; mt++){
      #pragma unroll
      for (int r = 0; r < 4; r++){
        long eidx = tb + mt*16 + q*4 + r;
        float v = (eidx < E) ? acc[mt][nt][r] : 0.f;
        s += v; qq += v*v;
      }
    }
    s += __shfl_xor(s, 16, 64); qq += __shfl_xor(qq, 16, 64);
    s += __shfl_xor(s, 32, 64); qq += __shfl_xor(qq, 32, 64);
    if (lane < 16){
      atomicAdd(&repl[r_idx*256 + choff + nt*16 + lane], s);
      atomicAdd(&repl[r_idx*256 + 128 + choff + nt*16 + lane], qq);
    }
  }
}
template<int ST>
static __device__ __forceinline__ void dumpC(f32x4_t acc[4][4], unsigned short* Cw,
                                             int c15, int q){
  #pragma unroll
  for (int mt = 0; mt < 4; mt++)
    #pragma unroll
    for (int nt = 0; nt < 4; nt++){
      int col = nt*16 + c15;
      #pragma unroll
      for (int r = 0; r < 4; r += 2){
        unsigned p = pk2(acc[mt][nt][r], acc[mt][nt][r+1]);
        int row = mt*16 + q*4 + r;
        Cw[row*ST + col]        = (unsigned short)p;
        Cw[(row + 1)*ST + col]  = (unsigned short)(p >> 16);
      }
    }
}
// segmented raw min/max over bucket-ordered tile; lane = channel
template<int ST>
static __device__ __forceinline__ void seg_walk(const unsigned short* Cw, const int* nodes,
                                                long tb, int E, int lane,
                                                unsigned* __restrict__ tmax,
                                                unsigned* __restrict__ tmin){
  long rem = (long)E - tb;
  int limit = rem >= 64 ? 64 : (rem > 0 ? (int)rem : 0);
  if (limit <= 0) return;
  int cur = nodes[0];
  float mx = -3.4e38f, mn = 3.4e38f;
  for (int k = 0; k < limit; k++){
    int nd = nodes[k];
    float v = bf2f(Cw[k*ST + lane]);
    if (nd != cur){
      atomicMax(&tmax[(size_t)cur*64 + lane], ordf(mx));
      atomicMin(&tmin[(size_t)cur*64 + lane], ordf(mn));
      cur = nd; mx = v; mn = v;
    } else {
      mx = fmaxf(mx, v); mn = fminf(mn, v);
    }
  }
  atomicMax(&tmax[(size_t)cur*64 + lane], ordf(mx));
  atomicMin(&tmin[(size_t)cur*64 + lane], ordf(mn));
}
// stage z1 (BN1+ReLU of m1 from pos) into A row
static __device__ __forceinline__ void stage_z1(const float* __restrict__ pos,
                                                const void* __restrict__ ei,
                                                long e_src, long e_dst, int N,
                                                const float* __restrict__ W1,
                                                const float* __restrict__ b1,
                                                const float* __restrict__ ss1,
                                                int m64, unsigned short* Ar){
  int si = clampi(ld_idx(ei, e_src, m64), 0, N-1);
  int di = clampi(ld_idx(ei, e_dst, m64), 0, N-1);
  float x0 = pos[di*3+0], x1 = pos[di*3+1], x2 = pos[di*3+2];
  float j0 = pos[si*3+0]-x0, j1 = pos[si*3+1]-x1, j2 = pos[si*3+2]-x2;
  #pragma unroll
  for (int c4 = 0; c4 < 64; c4 += 4){
    float zv[4];
    #pragma unroll
    for (int u = 0; u < 4; u++){
      int c = c4 + u;
      float m = b1[c];
      m = fmaf(x0, W1[c*6+0], m); m = fmaf(x1, W1[c*6+1], m); m = fmaf(x2, W1[c*6+2], m);
      m = fmaf(j0, W1[c*6+3], m); m = fmaf(j1, W1[c*6+4], m); m = fmaf(j2, W1[c*6+5], m);
      zv[u] = fmaxf(fmaf(m, ss1[c], ss1[64 + c]), 0.f);
    }
    uint2 pk;
    pk.x = pk2(zv[0], zv[1]);
    pk.y = pk2(zv[2], zv[3]);
    *(uint2*)&Ar[c4] = pk;
  }
}

// ---------- m2 stats only (natural edge order) ----------
__global__ void __launch_bounds__(128, 1)
k_m2stats(const float* __restrict__ pos, const void* __restrict__ ei,
          int E, int N, const int* dmode,
          const float* __restrict__ W1, const float* __restrict__ b1,
          const float* __restrict__ ss1,
          const float* __restrict__ W2, const float* __restrict__ b2,
          float* __restrict__ repl){
  __shared__ unsigned short A[2][64][72];
  int m64 = dmode[0];
  int wv = threadIdx.x >> 6, lane = threadIdx.x & 63;
  long tb = (long)blockIdx.x*128 + wv*64;
  long e = tb + lane;
  unsigned short* Ar = &A[wv][lane][0];
  if (e < E){
    stage_z1(pos, ei, e, (long)E + e, N, W1, b1, ss1, m64, Ar);
  } else {
    #pragma unroll
    for (int c4 = 0; c4 < 64; c4 += 4) *(uint2*)&Ar[c4] = make_uint2(0u, 0u);
  }
  __syncthreads();
  int c15 = lane & 15, q = lane >> 4;
  short8_t bf[4][2];
  loadB<2>(W2, c15, q, bf);
  f32x4_t acc[4][4];
  do_mfma<2, 72>(&A[wv][0][0], bf, b2, c15, q, acc);
  stats_acc(acc, tb, E, lane, q, (blockIdx.x*2 + wv) & 63, 0, repl);
}

// ---------- conv1 fused: z1 -> m2 -> bn2relu -> m3 -> stats + raw min/max agg ----------
__global__ void __launch_bounds__(128, 1)
k_conv1f(const float* __restrict__ pos, const void* __restrict__ ei,
         const int* __restrict__ bucket, const int* __restrict__ nodeof,
         int E, int N, const int* dmode,
         const float* __restrict__ W1, const float* __restrict__ b1,
         const float* __restrict__ ss1, const float* __restrict__ ss2,
         const float* __restrict__ W2, const float* __restrict__ b2,
         const float* __restrict__ W3, const float* __restrict__ b3,
         float* __restrict__ repl, unsigned* __restrict__ tmax, unsigned* __restrict__ tmin){
  __shared__ unsigned short A[2][64][72];
  __shared__ int nds[2][64];
  int m64 = dmode[0];
  int wv = threadIdx.x >> 6, lane = threadIdx.x & 63;
  long tb = (long)blockIdx.x*128 + wv*64;
  long t = tb + lane;
  unsigned short* Ar = &A[wv][lane][0];
  if (t < E){
    int p = bucket[t];
    nds[wv][lane] = nodeof[t];
    stage_z1(pos, ei, (long)p, (long)E + p, N, W1, b1, ss1, m64, Ar);
  } else {
    nds[wv][lane] = 0;
    #pragma unroll
    for (int c4 = 0; c4 < 64; c4 += 4) *(uint2*)&Ar[c4] = make_uint2(0u, 0u);
  }
  __syncthreads();
  int c15 = lane & 15, q = lane >> 4;
  unsigned short* Aw = &A[wv][0][0];
  f32x4_t acc[4][4];
  {
    short8_t bf[4][2];
    loadB<2>(W2, c15, q, bf);
    do_mfma<2, 72>(Aw, bf, b2, c15, q, acc);
  }
  #pragma unroll
  for (int nt = 0; nt < 4; nt++){
    int ch = nt*16 + c15;
    float sc = ss2[ch], sh = ss2[64 + ch];
    #pragma unroll
    for (int mt = 0; mt < 4; mt++)
      #pragma unroll
      for (int r = 0; r < 4; r++)
        acc[mt][nt][r] = fmaxf(fmaf(acc[mt][nt][r], sc, sh), 0.f);
  }
  __syncthreads();
  dumpC<72>(acc, Aw, c15, q);
  __syncthreads();
  {
    short8_t bf[4][2];
    loadB<2>(W3, c15, q, bf);
    do_mfma<2, 72>(Aw, bf, b3, c15, q, acc);
  }
  stats_acc(acc, tb, E, lane, q, (blockIdx.x*2 + wv) & 63, 0, repl);
  __syncthreads();
  dumpC<72>(acc, Aw, c15, q);
  __syncthreads();
  seg_walk<72>(Aw, &nds[wv][0], tb, E, lane, tmax, tmin);
}

// ---------- conv2 fused ----------
__global__ void __launch_bounds__(128, 1)
k_conv2f(const unsigned short* __restrict__ x1, const void* __restrict__ ei,
         const int* __restrict__ bucket, const int* __restrict__ nodeof,
         int E, int N, const int* dmode,
         const float* __restrict__ Wab, const float* __restrict__ b4,
         float* __restrict__ repl, unsigned* __restrict__ tmax, unsigned* __restrict__ tmin){
  __shared__ unsigned short A[2][64][136];
  __shared__ int nds[2][64];
  int m64 = dmode[0];
  int wv = threadIdx.x >> 6, lane = threadIdx.x & 63;
  long tb = (long)blockIdx.x*128 + wv*64;
  long t = tb + lane;
  unsigned short* Ar = &A[wv][lane][0];
  if (t < E){
    int p = bucket[t];
    nds[wv][lane] = nodeof[t];
    int si = clampi(ld_idx(ei, (long)p, m64), 0, N-1);
    int di = clampi(ld_idx(ei, (long)E + p, m64), 0, N-1);
    const uint4* xi4 = (const uint4*)(x1 + (size_t)di*64);
    const uint4* xj4 = (const uint4*)(x1 + (size_t)si*64);
    #pragma unroll
    for (int k = 0; k < 8; k++) *(uint4*)&Ar[k*8]      = xi4[k];
    #pragma unroll
    for (int k = 0; k < 8; k++) *(uint4*)&Ar[64 + k*8] = xj4[k];
  } else {
    nds[wv][lane] = 0;
    #pragma unroll
    for (int k = 0; k < 16; k++) *(uint4*)&Ar[k*8] = make_uint4(0u,0u,0u,0u);
  }
  __syncthreads();
  int c15 = lane & 15, q = lane >> 4;
  unsigned short* Aw = &A[wv][0][0];
  f32x4_t acc[4][4];
  {
    short8_t bf[4][4];
    loadB<4>(Wab, c15, q, bf);
    do_mfma<4, 136>(Aw, bf, b4, c15, q, acc);
  }
  stats_acc(acc, tb, E, lane, q, (blockIdx.x*2 + wv) & 63, 0, repl);
  __syncthreads();
  dumpC<136>(acc, Aw, c15, q);
  __syncthreads();
  seg_walk<136>(Aw, &nds[wv][0], tb, E, lane, tmax, tmin);
}

// ---------- apply BN post-aggregation ----------
__global__ void k_applybn(const unsigned* __restrict__ tmax, const unsigned* __restrict__ tmin,
                          const float* __restrict__ ss, long total,
                          unsigned short* __restrict__ xout){
  long i = (long)blockIdx.x*256 + threadIdx.x;
  if (i >= total) return;
  int c = (int)(i & 63);
  unsigned um = tmax[i];
  float out = 0.f;
  if (um != 0u){
    float sc = ss[c], sh = ss[64 + c];
    float v = (sc >= 0.f) ? iordf(um) : iordf(tmin[i]);
    out = fmaxf(fmaf(v, sc, sh), 0.f);
  }
  xout[i] = f2bf(out);
}

// ---------- lin5 (MFMA): y5 = cat(x1,x2)@W5^T + b5, fused BN5 stats (fixed offsets) ----------
__global__ void __launch_bounds__(128, 1)
k_lin5m(const unsigned short* __restrict__ x1, const unsigned short* __restrict__ x2,
        int N, const float* __restrict__ W5, const float* __restrict__ b5,
        unsigned short* __restrict__ y5, float* __restrict__ repl){
  __shared__ unsigned short A[2][64][136];
  __shared__ unsigned short Cb[2][64][72];
  int wv = threadIdx.x >> 6, lane = threadIdx.x & 63;
  long nb0 = (long)blockIdx.x*128 + wv*64;
  long n = nb0 + lane;
  unsigned short* Ar = &A[wv][lane][0];
  if (n < N){
    const uint4* a4 = (const uint4*)(x1 + (size_t)n*64);
    const uint4* b4 = (const uint4*)(x2 + (size_t)n*64);
    #pragma unroll
    for (int k = 0; k < 8; k++) *(uint4*)&Ar[k*8]      = a4[k];
    #pragma unroll
    for (int k = 0; k < 8; k++) *(uint4*)&Ar[64 + k*8] = b4[k];
  } else {
    #pragma unroll
    for (int k = 0; k < 16; k++) *(uint4*)&Ar[k*8] = make_uint4(0u,0u,0u,0u);
  }
  __syncthreads();
  int c15 = lane & 15, q = lane >> 4;
  int r_idx = (blockIdx.x*2 + wv) & 63;
  unsigned short* Aw = &A[wv][0][0];
  unsigned short* Cw = &Cb[wv][0][0];
  for (int h = 0; h < 2; h++){
    const float* Wp = W5 + (size_t)h*64*128;
    short8_t bf[4][4];
    loadB<4>(Wp, c15, q, bf);
    f32x4_t acc[4][4];
    do_mfma<4, 136>(Aw, bf, b5 + h*64, c15, q, acc);
    stats_acc(acc, nb0, N, lane, q, r_idx, h*64, repl);
    dumpC<72>(acc, Cw, c15, q);
    __syncthreads();
    int rl = lane >> 3, ch8 = lane & 7;
    #pragma unroll
    for (int pass = 0; pass < 8; pass++){
      int row = pass*8 + rl;
      long nn = nb0 + row;
      if (nn < N)
        *(uint4*)(y5 + (size_t)nn*128 + h*64 + ch8*8) = *(const uint4*)&Cw[row*72 + ch8*8];
    }
    __syncthreads();
  }
}

// ---------- pool ----------
__global__ void k_pool(const unsigned short* __restrict__ y5, const void* __restrict__ batch, int N,
                       const int* dmode, const float* __restrict__ ss5, unsigned int* __restrict__ pooled){
  int m64 = dmode[0];
  int c = threadIdx.x & 127;
  int par = threadIdx.x >> 7;
  int n0 = blockIdx.x*128;
  int n1 = min(n0 + 128, N);
  float sc = ss5[c], sh = ss5[128 + c];
  int curb = -1; float curm = 0.f;
  for (int n = n0 + par; n < n1; n += 2){
    int b = clampi(ld_idx(batch, (long)n, m64), 0, 63);
    float v = fmaf(bf2f(y5[(size_t)n*128 + c]), sc, sh);
    if (b != curb){
      if (curb >= 0) atomicMax(&pooled[curb*128 + c], __float_as_uint(fmaxf(curm, 0.f)));
      curb = b; curm = v;
    } else {
      curm = fmaxf(curm, v);
    }
  }
  if (curb >= 0) atomicMax(&pooled[curb*128 + c], __float_as_uint(fmaxf(curm, 0.f)));
}

// ---------- head ----------
__global__ void k_pooled2f(const unsigned int* __restrict__ pooled, float* __restrict__ pf){
  int i = blockIdx.x*256 + threadIdx.x;
  if (i < 8192) pf[i] = __uint_as_float(pooled[i]);
}

__global__ void k_linH(const float* __restrict__ X, const float* __restrict__ W,
                       const float* __restrict__ b, int CI, int CO, float* __restrict__ Y){
  int cell = blockIdx.x*256 + threadIdx.x;
  if (cell >= 64*CO) return;
  int r = cell / CO, c = cell - r*CO;
  const float* xr = X + r*CI;
  const float* wr = W + c*CI;
  float a = b[c];
  for (int j = 0; j < CI; j++) a = fmaf(xr[j], wr[j], a);
  Y[cell] = a;
}

__global__ void k_bnH(const float* __restrict__ Y, int CO,
                      const float* __restrict__ g, const float* __restrict__ be,
                      float* __restrict__ ss){
  int c = threadIdx.x;
  if (c >= CO) return;
  float s = 0.f;
  for (int r = 0; r < 64; r++) s += Y[r*CO + c];
  float mean = s * (1.f/64.f);
  float q = 0.f;
  for (int r = 0; r < 64; r++){ float d = Y[r*CO + c] - mean; q += d*d; }
  float var = fmaxf(q * (1.f/64.f), 0.f);
  float inv = rsqrtf(var + EPS_BN);
  float sc = g[c] * inv;
  ss[c] = sc;
  ss[CO + c] = be[c] - mean*sc;
}

__global__ void k_bnreluH(float* __restrict__ Y, int CO, const float* __restrict__ ss){
  int cell = blockIdx.x*256 + threadIdx.x;
  if (cell >= 64*CO) return;
  int c = cell % CO;
  Y[cell] = fmaxf(fmaf(Y[cell], ss[c], ss[CO + c]), 0.f);
}

__global__ void k_logsm(const float* __restrict__ Z, float* __restrict__ out){
  int r = threadIdx.x;   // 64 threads
  const float* zr = Z + r*40;
  float m = zr[0];
  for (int c = 1; c < 40; c++) m = fmaxf(m, zr[c]);
  float s = 0.f;
  for (int c = 0; c < 40; c++) s += expf(zr[c] - m);
  float ls = logf(s);
  for (int c = 0; c < 40; c++) out[r*40 + c] = zr[c] - m - ls;
}

// ---------- launch ----------
extern "C" void kernel_launch(void* const* d_in, const int* in_sizes, int n_in,
                              void* d_out, int out_size, void* d_ws, size_t ws_size,
                              hipStream_t stream) {
  const void* pos   = d_in[0];
  const void* ei    = d_in[1];
  const void* batch = d_in[2];
  (void)n_in;

  const int N = in_sizes[0] / 3;
  const int E = in_sizes[1] / 2;

  // ---- workspace layout ----
  auto al = [](size_t x){ return (x + 255) & ~(size_t)255; };
  char* w = (char*)d_ws;
  size_t o = 0;
  float* repl = (float*)(w + o);                 o += (size_t)64*256*4;
  unsigned int* pooled = (unsigned int*)(w + o); o += (size_t)64*128*4;
  int* deg = (int*)(w + o);                      o += al((size_t)4*N);
  size_t zero_bytes = o;
  unsigned* tmaxA = (unsigned*)(w + o);          o += (size_t)64*N*4;
  unsigned* tmaxB = (unsigned*)(w + o);          o += (size_t)64*N*4;
  size_t tmax_bytes = (size_t)64*N*4*2;
  unsigned* tminA = (unsigned*)(w + o);          o += (size_t)64*N*4;
  unsigned* tminB = (unsigned*)(w + o);          o += (size_t)64*N*4;
  size_t tmin_bytes = (size_t)64*N*4*2;
  int* dmode = (int*)(w + o);                    o += 256;
  int* offs = (int*)(w + o);                     o += al((size_t)4*(N + 1));
  int* cursor = (int*)(w + o);                   o += al((size_t)4*N);
  int* part = (int*)(w + o);                     o += 4096;
  int* bucket = (int*)(w + o);                   o += al((size_t)4*E);
  int* nodeof = (int*)(w + o);                   o += al((size_t)4*E);
  float* ss1 = (float*)(w + o);                  o += 1024;
  float* ss2 = (float*)(w + o);                  o += 1024;
  float* ss3 = (float*)(w + o);                  o += 1024;
  float* ss4 = (float*)(w + o);                  o += 1024;
  float* ss5 = (float*)(w + o);                  o += 1024;
  float* ssH = (float*)(w + o);                  o += 1024;
  float* Wab = (float*)(w + o);                  o += (size_t)8192*4;
  float* pooledF = (float*)(w + o);              o += (size_t)8192*4;
  float* Y6 = (float*)(w + o);                   o += (size_t)8192*4;
  float* Y7 = (float*)(w + o);                   o += (size_t)8192*4;
  float* Zl = (float*)(w + o);                   o += al((size_t)2560*4);
  // fp32 expansion region
  float* expBase = (float*)(w + o);
  float* ep = expBase;
  float* epos = ep; ep += (size_t)3*N;
  float* eW[9], *eb[9], *eg[9], *ebe[9];
  const int wsz[9] = {0, 64*6, 64*64, 64*64, 64*128, 128*128, 128*128, 128*128, 40*128};
  const int bsz[9] = {0, 64, 64, 64, 64, 128, 128, 128, 40};
  for (int i = 1; i <= 8; i++){
    eW[i] = ep; ep += wsz[i];
    eb[i] = ep; ep += bsz[i];
    if (i < 8){ eg[i] = ep; ep += bsz[i]; ebe[i] = ep; ep += bsz[i]; }
  }
  long expCount = (long)(ep - expBase);
  o += al((size_t)expCount * 4);
  unsigned short* x1b = (unsigned short*)(w + o); o += al((size_t)2*64*N);
  unsigned short* x2b = (unsigned short*)(w + o); o += al((size_t)2*64*N);
  unsigned short* y5b = (unsigned short*)(w + o); o += al((size_t)2*128*N);

  float* out_f = (float*)d_out;
  if (ws_size < o){
    k_sentinel<<<cdiv(out_size,256), 256, 0, stream>>>(out_f, out_size);
    return;
  }

  hipMemsetAsync(w, 0, zero_bytes, stream);
  hipMemsetAsync(tmaxA, 0x00, tmax_bytes, stream);
  hipMemsetAsync(tminA, 0xFF, tmin_bytes, stream);
  k_detect<<<1, 256, 0, stream>>>(ei, pos, dmode);

  // expand all float inputs -> fp32
  ExpArgs ea;
  int it = 0;
  ea.it[it++] = {pos, epos, 3*N};
  int di_idx = 3;
  for (int i = 1; i <= 8; i++){
    ea.it[it++] = {d_in[di_idx++], eW[i], wsz[i]};
    ea.it[it++] = {d_in[di_idx++], eb[i], bsz[i]};
    if (i < 8){
      ea.it[it++] = {d_in[di_idx++], eg[i], bsz[i]};
      ea.it[it++] = {d_in[di_idx++], ebe[i], bsz[i]};
    }
  }
  k_expand<<<dim3(cdiv(3*N,256), 31), 256, 0, stream>>>(ea, it, dmode);
  k_prepW4<<<32, 256, 0, stream>>>(eW[4], Wab);

  const int nb = cdiv(N, 1024);
  // CSR build
  k_hist<<<cdiv(E,256), 256, 0, stream>>>(ei, E, N, dmode, deg);
  k_scan1<<<nb, 1024, 0, stream>>>(deg, N, offs, part);
  k_scan2<<<1, 1024, 0, stream>>>(part, nb);
  k_scan3<<<nb, 1024, 0, stream>>>(deg, part, N, E, offs, cursor);
  k_fill<<<cdiv(E,256), 256, 0, stream>>>(ei, E, N, dmode, cursor, bucket, nodeof);

  // conv1: m1 stats -> m2 stats -> fused (m2 recompute, bn2relu, m3, stats, raw agg)
  k_m1stats<<<cdiv(E,2048), 256, 0, stream>>>(epos, ei, E, N, dmode, eW[1], eb[1], repl);
  k_finalize<<<1, 128, 0, stream>>>(repl, 64, (float)E, eg[1], ebe[1], ss1);
  k_m2stats<<<cdiv(E,128), 128, 0, stream>>>(epos, ei, E, N, dmode, eW[1], eb[1], ss1,
                                             eW[2], eb[2], repl);
  k_finalize<<<1, 128, 0, stream>>>(repl, 64, (float)E, eg[2], ebe[2], ss2);
  k_conv1f<<<cdiv(E,128), 128, 0, stream>>>(epos, ei, bucket, nodeof, E, N, dmode,
                                            eW[1], eb[1], ss1, ss2, eW[2], eb[2],
                                            eW[3], eb[3], repl, tmaxA, tminA);
  k_finalize<<<1, 128, 0, stream>>>(repl, 64, (float)E, eg[3], ebe[3], ss3);
  k_applybn<<<cdiv(N*64,256), 256, 0, stream>>>(tmaxA, tminA, ss3, (long)N*64, x1b);

  // conv2 fused
  k_conv2f<<<cdiv(E,128), 128, 0, stream>>>(x1b, ei, bucket, nodeof, E, N, dmode,
                                            Wab, eb[4], repl, tmaxB, tminB);
  k_finalize<<<1, 128, 0, stream>>>(repl, 64, (float)E, eg[4], ebe[4], ss4);
  k_applybn<<<cdiv(N*64,256), 256, 0, stream>>>(tmaxB, tminB, ss4, (long)N*64, x2b);

  // lin5 (MFMA, fused BN5 stats with correct channel offsets) + pool
  k_lin5m<<<cdiv(N,128), 128, 0, stream>>>(x1b, x2b, N, eW[5], eb[5], y5b, repl);
  k_finalize<<<1, 128, 0, stream>>>(repl, 128, (float)N, eg[5], ebe[5], ss5);
  k_pool<<<cdiv(N,128), 256, 0, stream>>>(y5b, batch, N, dmode, ss5, pooled);

  // head
  k_pooled2f<<<32, 256, 0, stream>>>(pooled, pooledF);
  k_linH<<<32, 256, 0, stream>>>(pooledF, eW[6], eb[6], 128, 128, Y6);
  k_bnH<<<1, 128, 0, stream>>>(Y6, 128, eg[6], ebe[6], ssH);
  k_bnreluH<<<32, 256, 0, stream>>>(Y6, 128, ssH);
  k_linH<<<32, 256, 0, stream>>>(Y6, eW[7], eb[7], 128, 128, Y7);
  k_bnH<<<1, 128, 0, stream>>>(Y7, 128, eg[7], ebe[7], ssH);
  k_bnreluH<<<32, 256, 0, stream>>>(Y7, 128, ssH);
  k_linH<<<10, 256, 0, stream>>>(Y7, eW[8], eb[8], 128, 40, Zl);
  k_logsm<<<1, 64, 0, stream>>>(Zl, out_f);
}